// Round 4
// baseline (381.123 us; speedup 1.0000x reference)
//
#include <hip/hip_runtime.h>
#include <hip/hip_cooperative_groups.h>
#include <math.h>

namespace cg = cooperative_groups;

namespace {

constexpr int H = 1024;
constexpr int W = 1024;
constexpr int HW = H * W;
constexpr int TILE = 64;             // output tile edge
constexpr int HALO = 8;              // steps fused per phase
constexpr int P = TILE + 2 * HALO;   // 80
constexpr int TSTEP = 8;
constexpr int NPHASE = 8;            // 8 phases x 8 steps = 64 steps
constexpr int NTX = W / TILE;        // 16
constexpr int NTHREADS = 512;        // 8 waves; 1 block/CU (LDS-capped)
constexpr int PITCH = P + 2;         // 82 float2/row; +16B pad shifts banks 4/row

__device__ __forceinline__ float clampf(float v, float lo, float hi) {
    return fminf(fmaxf(v, lo), hi);
}
__device__ __forceinline__ float4 ld4(const float2* p) {
    return *reinterpret_cast<const float4*>(p);
}

// 64 Gray-Scott steps: 8 phases of 8 LDS-fused steps, one cooperative launch.
// Per phase: load 80x80 halo tile -> 8 steps (register-rolling down columns,
// shrinking bounds; garbage ring never reaches the interior) -> store 64x64
// interior -> grid-wide sync (fences make cross-XCD stores visible).
__global__ __launch_bounds__(NTHREADS, 1) void gs_fused(
    const float* __restrict__ U0, const float* __restrict__ V0,
    float* __restrict__ wsU, float* __restrict__ wsV,
    float* __restrict__ outU, float* __restrict__ outV,
    const float* __restrict__ pLogDu, const float* __restrict__ pLogDv,
    const float* __restrict__ pf, const float* __restrict__ pk,
    float invDX2, float invDY2, float dt)
{
    __shared__ __align__(16) float2 sUV[2][P * PITCH];   // 102.5 KB

    const int tid = threadIdx.x;
    const int bx = blockIdx.x & (NTX - 1);
    const int by = blockIdx.x >> 4;
    const int gx0 = bx * TILE - HALO;
    const int gy0 = by * TILE - HALO;

    const float Du = clampf(expf(pLogDu[0]), 0.001f, 1.0f);
    const float Dv = clampf(expf(pLogDv[0]), 0.001f, 1.0f);
    const float f = pf[0], k = pk[0];
    const float fk = f + k;

    cg::grid_group grid = cg::this_grid();

    for (int p = 0; p < NPHASE; ++p) {
        // ping-pong: p0 in->ws, p1 ws->out, p2 out->ws, ... p7 ws->out (final)
        const float* __restrict__ srcU = (p == 0) ? U0 : ((p & 1) ? wsU : outU);
        const float* __restrict__ srcV = (p == 0) ? V0 : ((p & 1) ? wsV : outV);
        float* __restrict__ dstU = (p & 1) ? outU : wsU;
        float* __restrict__ dstV = (p & 1) ? outV : wsV;

        // ---- load 80x80 halo'd tile (periodic wrap), interleave U,V ----
        for (int t = tid; t < P * (P / 4); t += NTHREADS) {   // 1600 strips
            const int r  = t / (P / 4);
            const int c4 = (t - r * (P / 4)) * 4;
            const int gy = (gy0 + r) & (H - 1);
            const int gx = (gx0 + c4) & (W - 1);   // 4-aligned, no mid-vec wrap
            const float4 u4 = *reinterpret_cast<const float4*>(srcU + gy * W + gx);
            const float4 v4 = *reinterpret_cast<const float4*>(srcV + gy * W + gx);
            float4* dst = reinterpret_cast<float4*>(&sUV[0][r * PITCH + c4]);
            dst[0] = make_float4(clampf(u4.x, 0.f, 2.f), clampf(v4.x, 0.f, 2.f),
                                 clampf(u4.y, 0.f, 2.f), clampf(v4.y, 0.f, 2.f));
            dst[1] = make_float4(clampf(u4.z, 0.f, 2.f), clampf(v4.z, 0.f, 2.f),
                                 clampf(u4.w, 0.f, 2.f), clampf(v4.w, 0.f, 2.f));
        }
        __syncthreads();

        // ---- 8 steps; threads walk columns, rolling N/C/S rows in registers ----
        int b = 0;
#pragma unroll
        for (int s = 1; s <= TSTEP; ++s) {
            const float2* __restrict__ cb = sUV[b];
            float2* __restrict__ nb = sUV[b ^ 1];

            const int rlo   = s;                       // rows [s, 79-s]
            const int nrows = P - 2 * s;
            const int c4lo  = s & ~3;                  // strips covering [s,79-s]
            const int c4hi  = (P - 1 - s) & ~3;
            const int nc    = (c4hi - c4lo) / 4 + 1;   // 20/18/16 (compile-time)
            const int nwalk = NTHREADS / nc;           // 25/28/32
            const int itmax = (nrows + nwalk - 1) / nwalk;   // 4/3/2

            const int col = tid % nc;
            const int wk  = tid / nc;
            const bool active = (wk < nwalk);
            const int r0 = rlo + (nrows * wk) / nwalk;
            const int r1 = rlo + (nrows * (wk + 1)) / nwalk;
            const int c4 = c4lo + col * 4;
            const int lc = (c4 > 0) ? c4 - 1 : 0;
            const int rc = (c4 + 4 < P) ? c4 + 4 : P - 1;

            float4 n01, n23, c01, c23;
            if (active) {
                const float2* rN = cb + (r0 - 1) * PITCH;
                const float2* rC = cb + r0 * PITCH;
                n01 = ld4(rN + c4); n23 = ld4(rN + c4 + 2);
                c01 = ld4(rC + c4); c23 = ld4(rC + c4 + 2);
            }
#pragma unroll
            for (int it = 0; it < itmax; ++it) {
                const int r = r0 + it;
                if (active && r < r1) {
                    const float2* rS = cb + (r + 1) * PITCH;
                    const float2* rC = cb + r * PITCH;
                    const float4 s01 = ld4(rS + c4);
                    const float4 s23 = ld4(rS + c4 + 2);
                    const float2 eL = rC[lc];
                    const float2 eR = rC[rc];

                    const float u[6]   = { eL.x, c01.x, c01.z, c23.x, c23.z, eR.x };
                    const float v[6]   = { eL.y, c01.y, c01.w, c23.y, c23.w, eR.y };
                    const float unn[4] = { n01.x, n01.z, n23.x, n23.z };
                    const float vnn[4] = { n01.y, n01.w, n23.y, n23.w };
                    const float uss[4] = { s01.x, s01.z, s23.x, s23.z };
                    const float vss[4] = { s01.y, s01.w, s23.y, s23.w };

                    float ou[4], ov[4];
#pragma unroll
                    for (int e = 0; e < 4; ++e) {
                        const float uc = u[e + 1];
                        const float vc = v[e + 1];
                        // state already in [0,2]: clamped at load & every store
                        float lu = (u[e] + u[e + 2] - 2.0f * uc) * invDX2
                                 + (unn[e] + uss[e] - 2.0f * uc) * invDY2;
                        float lv = (v[e] + v[e + 2] - 2.0f * vc) * invDX2
                                 + (vnn[e] + vss[e] - 2.0f * vc) * invDY2;
                        lu = clampf(lu, -10.0f, 10.0f);
                        lv = clampf(lv, -10.0f, 10.0f);
                        const float uvv = uc * vc * vc;
                        const float du = clampf(fmaf(Du, lu, fmaf(f, 1.0f - uc, -uvv)), -1.0f, 1.0f);
                        const float dv = clampf(fmaf(Dv, lv, uvv - fk * vc), -1.0f, 1.0f);
                        ou[e] = clampf(fmaf(du, dt, uc), 0.0f, 2.0f);
                        ov[e] = clampf(fmaf(dv, dt, vc), 0.0f, 2.0f);
                    }
                    float4* dst = reinterpret_cast<float4*>(nb + r * PITCH + c4);
                    dst[0] = make_float4(ou[0], ov[0], ou[1], ov[1]);
                    dst[1] = make_float4(ou[2], ov[2], ou[3], ov[3]);

                    n01 = c01; n23 = c23;   // roll down one row
                    c01 = s01; c23 = s23;
                }
            }
            __syncthreads();
            b ^= 1;
        }

        // ---- store the valid 64x64 interior, de-interleaving (b == 0 here) ----
        const float2* __restrict__ fb = sUV[b];
        for (int i = tid; i < TILE * (TILE / 4); i += NTHREADS) {   // 1024 strips
            const int r  = i / (TILE / 4);
            const int c4 = (i - r * (TILE / 4)) * 4;
            const float4* src = reinterpret_cast<const float4*>(
                fb + (r + HALO) * PITCH + (c4 + HALO));
            const float4 a = src[0];
            const float4 q = src[1];
            const int go = (by * TILE + r) * W + bx * TILE + c4;
            *reinterpret_cast<float4*>(dstU + go) = make_float4(a.x, a.z, q.x, q.z);
            *reinterpret_cast<float4*>(dstV + go) = make_float4(a.y, a.w, q.y, q.w);
        }

        if (p != NPHASE - 1) grid.sync();   // all stores visible before next load
    }
}

} // namespace

extern "C" void kernel_launch(void* const* d_in, const int* in_sizes, int n_in,
                              void* d_out, int out_size, void* d_ws, size_t ws_size,
                              hipStream_t stream) {
    const float* U0     = (const float*)d_in[0];
    const float* V0     = (const float*)d_in[1];
    const float* pLogDu = (const float*)d_in[2];
    const float* pLogDv = (const float*)d_in[3];
    const float* pf     = (const float*)d_in[4];
    const float* pk     = (const float*)d_in[5];
    // d_in[6] = steps (int32) — fixed at 64 by the problem definition.

    float* wsU  = (float*)d_ws;   // 4 MB
    float* wsV  = wsU + HW;       // 4 MB
    float* outU = (float*)d_out;  // output layout: [U (HW) | V (HW)]
    float* outV = outU + HW;

    const double dx  = 1.0 / (W - 1);
    const double dy  = 1.0 / (H - 1);
    const double dx2 = dx * dx;
    const double dy2 = dy * dy;
    float invdx2 = (float)(1.0 / dx2);
    float invdy2 = (float)(1.0 / dy2);
    float dtf    = (float)(0.1 * ((dx2 < dy2) ? dx2 : dy2) / (4.0 * 0.16));

    void* args[] = {
        (void*)&U0, (void*)&V0, (void*)&wsU, (void*)&wsV, (void*)&outU, (void*)&outV,
        (void*)&pLogDu, (void*)&pLogDv, (void*)&pf, (void*)&pk,
        (void*)&invdx2, (void*)&invdy2, (void*)&dtf
    };
    hipLaunchCooperativeKernel((const void*)gs_fused,
                               dim3((H / TILE) * (W / TILE)), dim3(NTHREADS),
                               args, 0, stream);
}

// Round 5
// 146.300 us; speedup vs baseline: 2.6051x; 2.6051x over previous
//
#include <hip/hip_runtime.h>
#include <math.h>

namespace {

constexpr int H = 1024;
constexpr int W = 1024;
constexpr int HW = H * W;
constexpr int STEPS = 64;            // fixed by setup_inputs()
constexpr int TILE = 64;             // output tile edge
constexpr int HALO = 8;              // = steps fused per launch
constexpr int P = TILE + 2 * HALO;   // 80
constexpr int TSTEP = 8;             // time steps per kernel launch
constexpr int NLAUNCH = STEPS / TSTEP;
constexpr int NTX = W / TILE;        // 16 tiles per dim
constexpr int NTHREADS = 1024;       // 16 waves = 4/SIMD (latency hiding)
constexpr int PITCH = P + 2;         // 82 float2/row; +16B pad shifts banks 4/row

__device__ __forceinline__ float clampf(float v, float lo, float hi) {
    return fminf(fmaxf(v, lo), hi);
}
__device__ __forceinline__ float4 ld4(const float2* p) {
    return *reinterpret_cast<const float4*>(p);
}

// 8 fused Gray-Scott steps on a 64x64 tile, halo 8, U/V interleaved as float2
// in double-buffered LDS. Step s computes only rows/cols [s, 79-s]; each thread
// owns a 2-row x 4-col block (amortizes N/S row reads). The garbage ring outside
// the shrinking valid region is never read by later steps.
__global__ __launch_bounds__(NTHREADS) void gs_tile(
    const float* __restrict__ Uin, const float* __restrict__ Vin,
    float* __restrict__ Uout, float* __restrict__ Vout,
    const float* __restrict__ pLogDu, const float* __restrict__ pLogDv,
    const float* __restrict__ pf, const float* __restrict__ pk,
    float invDX2, float invDY2, float dt)
{
    __shared__ __align__(16) float2 sUV[2][P * PITCH];   // 102.5 KB -> 1 block/CU

    const int tid = threadIdx.x;
    const int bx = blockIdx.x & (NTX - 1);
    const int by = blockIdx.x >> 4;
    const int gx0 = bx * TILE - HALO;
    const int gy0 = by * TILE - HALO;

    const float Du = clampf(expf(pLogDu[0]), 0.001f, 1.0f);
    const float Dv = clampf(expf(pLogDv[0]), 0.001f, 1.0f);
    const float f = pf[0], k = pk[0];
    const float fk = f + k;

    // ---- load 80x80 halo'd tile (periodic wrap), interleave U,V ----
    for (int t = tid; t < P * (P / 4); t += NTHREADS) {   // 1600 4-px strips
        const int r  = t / (P / 4);
        const int c4 = (t - r * (P / 4)) * 4;
        const int gy = (gy0 + r) & (H - 1);
        const int gx = (gx0 + c4) & (W - 1);              // 4-aligned, no mid-vec wrap
        const float4 u4 = *reinterpret_cast<const float4*>(Uin + gy * W + gx);
        const float4 v4 = *reinterpret_cast<const float4*>(Vin + gy * W + gx);
        float4* dst = reinterpret_cast<float4*>(&sUV[0][r * PITCH + c4]);
        dst[0] = make_float4(clampf(u4.x, 0.f, 2.f), clampf(v4.x, 0.f, 2.f),
                             clampf(u4.y, 0.f, 2.f), clampf(v4.y, 0.f, 2.f));
        dst[1] = make_float4(clampf(u4.z, 0.f, 2.f), clampf(v4.z, 0.f, 2.f),
                             clampf(u4.w, 0.f, 2.f), clampf(v4.w, 0.f, 2.f));
    }
    __syncthreads();

    // ---- 8 fused steps; s-loop unrolled so per-step bounds are literals ----
    int b = 0;
#pragma unroll
    for (int s = 1; s <= TSTEP; ++s) {
        const float2* __restrict__ cb = sUV[b];
        float2* __restrict__ nb = sUV[b ^ 1];

        const int rlo   = s;                       // rows [s, 79-s], count even
        const int npair = (P - 2 * s) / 2;         // 2-row blocks per column
        const int c4lo  = s & ~3;                  // strips covering cols [s,79-s]
        const int c4hi  = (P - 1 - s) & ~3;
        const int nc    = (c4hi - c4lo) / 4 + 1;   // 20/20/20/18/18/18/18/16
        const int tasks = npair * nc;              // max 780 < 1024: single pass

        if (tid < tasks) {
            const int pr  = tid / nc;              // const divisor -> magic mul
            const int row = rlo + 2 * pr;
            const int c4  = c4lo + (tid - pr * nc) * 4;

            const float2* rA = cb + row * PITCH;   // rows row-1 .. row+2
            const float2* rN = rA - PITCH;
            const float2* rB = rA + PITCH;
            const float2* rS = rB + PITCH;
            const int lc = (c4 > 0) ? c4 - 1 : 0;
            const int rc = (c4 + 4 < P) ? c4 + 4 : P - 1;

            const float4 n01 = ld4(rN + c4), n23 = ld4(rN + c4 + 2);
            const float4 a01 = ld4(rA + c4), a23 = ld4(rA + c4 + 2);
            const float4 b01 = ld4(rB + c4), b23 = ld4(rB + c4 + 2);
            const float4 s01 = ld4(rS + c4), s23 = ld4(rS + c4 + 2);
            const float2 eLa = rA[lc], eRa = rA[rc];
            const float2 eLb = rB[lc], eRb = rB[rc];

            // row A (uses N and B as neighbors), row B (uses A and S)
            const float ua[6]  = { eLa.x, a01.x, a01.z, a23.x, a23.z, eRa.x };
            const float va[6]  = { eLa.y, a01.y, a01.w, a23.y, a23.w, eRa.y };
            const float ub[6]  = { eLb.x, b01.x, b01.z, b23.x, b23.z, eRb.x };
            const float vb[6]  = { eLb.y, b01.y, b01.w, b23.y, b23.w, eRb.y };
            const float unn[4] = { n01.x, n01.z, n23.x, n23.z };
            const float vnn[4] = { n01.y, n01.w, n23.y, n23.w };
            const float uss[4] = { s01.x, s01.z, s23.x, s23.z };
            const float vss[4] = { s01.y, s01.w, s23.y, s23.w };

            float oua[4], ova[4], oub[4], ovb[4];
#pragma unroll
            for (int e = 0; e < 4; ++e) {
                // ---- row A ----
                {
                    const float uc = ua[e + 1], vc = va[e + 1];
                    float lu = (ua[e] + ua[e + 2] - 2.0f * uc) * invDX2
                             + (unn[e] + ub[e + 1] - 2.0f * uc) * invDY2;
                    float lv = (va[e] + va[e + 2] - 2.0f * vc) * invDX2
                             + (vnn[e] + vb[e + 1] - 2.0f * vc) * invDY2;
                    lu = clampf(lu, -10.0f, 10.0f);
                    lv = clampf(lv, -10.0f, 10.0f);
                    const float uvv = uc * vc * vc;
                    const float du = clampf(fmaf(Du, lu, fmaf(f, 1.0f - uc, -uvv)), -1.0f, 1.0f);
                    const float dv = clampf(fmaf(Dv, lv, uvv - fk * vc), -1.0f, 1.0f);
                    oua[e] = clampf(fmaf(du, dt, uc), 0.0f, 2.0f);
                    ova[e] = clampf(fmaf(dv, dt, vc), 0.0f, 2.0f);
                }
                // ---- row B ----
                {
                    const float uc = ub[e + 1], vc = vb[e + 1];
                    float lu = (ub[e] + ub[e + 2] - 2.0f * uc) * invDX2
                             + (ua[e + 1] + uss[e] - 2.0f * uc) * invDY2;
                    float lv = (vb[e] + vb[e + 2] - 2.0f * vc) * invDX2
                             + (va[e + 1] + vss[e] - 2.0f * vc) * invDY2;
                    lu = clampf(lu, -10.0f, 10.0f);
                    lv = clampf(lv, -10.0f, 10.0f);
                    const float uvv = uc * vc * vc;
                    const float du = clampf(fmaf(Du, lu, fmaf(f, 1.0f - uc, -uvv)), -1.0f, 1.0f);
                    const float dv = clampf(fmaf(Dv, lv, uvv - fk * vc), -1.0f, 1.0f);
                    oub[e] = clampf(fmaf(du, dt, uc), 0.0f, 2.0f);
                    ovb[e] = clampf(fmaf(dv, dt, vc), 0.0f, 2.0f);
                }
            }
            float4* dstA = reinterpret_cast<float4*>(nb + row * PITCH + c4);
            dstA[0] = make_float4(oua[0], ova[0], oua[1], ova[1]);
            dstA[1] = make_float4(oua[2], ova[2], oua[3], ova[3]);
            float4* dstB = reinterpret_cast<float4*>(nb + (row + 1) * PITCH + c4);
            dstB[0] = make_float4(oub[0], ovb[0], oub[1], ovb[1]);
            dstB[1] = make_float4(oub[2], ovb[2], oub[3], ovb[3]);
        }
        b ^= 1;
        __syncthreads();
    }

    // ---- store the valid 64x64 interior, de-interleaving ----
    const float2* __restrict__ fb = sUV[b];
    for (int i = tid; i < TILE * (TILE / 4); i += NTHREADS) {   // 1024 strips
        const int r  = i / (TILE / 4);
        const int c4 = (i - r * (TILE / 4)) * 4;
        const float4* src = reinterpret_cast<const float4*>(
            fb + (r + HALO) * PITCH + (c4 + HALO));
        const float4 a = src[0];
        const float4 q = src[1];
        const int go = (by * TILE + r) * W + bx * TILE + c4;
        *reinterpret_cast<float4*>(Uout + go) = make_float4(a.x, a.z, q.x, q.z);
        *reinterpret_cast<float4*>(Vout + go) = make_float4(a.y, a.w, q.y, q.w);
    }
}

} // namespace

extern "C" void kernel_launch(void* const* d_in, const int* in_sizes, int n_in,
                              void* d_out, int out_size, void* d_ws, size_t ws_size,
                              hipStream_t stream) {
    const float* U0     = (const float*)d_in[0];
    const float* V0     = (const float*)d_in[1];
    const float* pLogDu = (const float*)d_in[2];
    const float* pLogDv = (const float*)d_in[3];
    const float* pf     = (const float*)d_in[4];
    const float* pk     = (const float*)d_in[5];
    // d_in[6] = steps (int32) — fixed at 64 by the problem definition.

    float* wsU  = (float*)d_ws;   // 4 MB
    float* wsV  = wsU + HW;       // 4 MB
    float* outU = (float*)d_out;  // output layout: [U (HW) | V (HW)]
    float* outV = outU + HW;

    const double dx  = 1.0 / (W - 1);
    const double dy  = 1.0 / (H - 1);
    const double dx2 = dx * dx;
    const double dy2 = dy * dy;
    const float invdx2 = (float)(1.0 / dx2);
    const float invdy2 = (float)(1.0 / dy2);
    const float dtf    = (float)(0.1 * ((dx2 < dy2) ? dx2 : dy2) / (4.0 * 0.16));

    const int grid = (H / TILE) * (W / TILE);   // 256 blocks = 1 per CU

    // 8 launches of 8 fused steps, ping-pong ws <-> d_out; launch 7 (odd)
    // leaves the final state exactly in d_out.
    const float* cu = U0;
    const float* cv = V0;
    for (int l = 0; l < NLAUNCH; ++l) {
        float* nu;
        float* nv;
        if (l & 1) { nu = outU; nv = outV; }
        else       { nu = wsU;  nv = wsV;  }
        gs_tile<<<grid, NTHREADS, 0, stream>>>(cu, cv, nu, nv,
                                               pLogDu, pLogDv, pf, pk,
                                               invdx2, invdy2, dtf);
        cu = nu; cv = nv;
    }
}

// Round 6
// 133.794 us; speedup vs baseline: 2.8486x; 1.0935x over previous
//
#include <hip/hip_runtime.h>
#include <math.h>

namespace {

constexpr int H = 1024;
constexpr int W = 1024;
constexpr int HW = H * W;
constexpr int STEPS = 64;            // fixed by setup_inputs()
constexpr int TILE = 64;             // output tile edge
constexpr int HALO = 16;             // = steps fused per launch
constexpr int P = TILE + 2 * HALO;   // 96
constexpr int TSTEP = 16;            // time steps per kernel launch
constexpr int NLAUNCH = STEPS / TSTEP;   // 4
constexpr int NTX = W / TILE;        // 16 tiles per dim
constexpr int NTHREADS = 1024;       // 16 waves = 4/SIMD
constexpr int PITCH = P + 2;         // 98 float2/row; +16B pad shifts banks 4/row

__device__ __forceinline__ float clampf(float v, float lo, float hi) {
    return fminf(fmaxf(v, lo), hi);
}
__device__ __forceinline__ float4 ld4(const float2* p) {
    return *reinterpret_cast<const float4*>(p);
}

// 16 fused Gray-Scott steps on a 64x64 tile, halo 16, U/V interleaved as
// float2 in double-buffered LDS (147 KB). Step s computes only rows/cols
// [s, 95-s]; each thread task is a 2-row x 4-col block. The garbage ring
// outside the shrinking valid region is clamped-finite and never read by
// later steps. Steps are grouped by constant strip-count nc so the per-task
// division is a compile-time magic-mul without 16x code bloat.
__global__ __launch_bounds__(NTHREADS) void gs_tile(
    const float* __restrict__ Uin, const float* __restrict__ Vin,
    float* __restrict__ Uout, float* __restrict__ Vout,
    const float* __restrict__ pLogDu, const float* __restrict__ pLogDv,
    const float* __restrict__ pf, const float* __restrict__ pk,
    float invDX2, float invDY2, float dt)
{
    __shared__ __align__(16) float2 sUV[2][P * PITCH];   // 2 x 73.5 KB = 147 KB

    const int tid = threadIdx.x;
    const int bx = blockIdx.x & (NTX - 1);
    const int by = blockIdx.x >> 4;
    const int gx0 = bx * TILE - HALO;
    const int gy0 = by * TILE - HALO;

    const float Du = clampf(expf(pLogDu[0]), 0.001f, 1.0f);
    const float Dv = clampf(expf(pLogDv[0]), 0.001f, 1.0f);
    const float f = pf[0], k = pk[0];
    const float fk = f + k;

    // ---- load 96x96 halo'd tile (periodic wrap), interleave U,V ----
    for (int t = tid; t < P * (P / 4); t += NTHREADS) {   // 2304 4-px strips
        const int r  = t / (P / 4);
        const int c4 = (t - r * (P / 4)) * 4;
        const int gy = (gy0 + r) & (H - 1);
        const int gx = (gx0 + c4) & (W - 1);              // 4-aligned, no mid-vec wrap
        const float4 u4 = *reinterpret_cast<const float4*>(Uin + gy * W + gx);
        const float4 v4 = *reinterpret_cast<const float4*>(Vin + gy * W + gx);
        float4* dst = reinterpret_cast<float4*>(&sUV[0][r * PITCH + c4]);
        dst[0] = make_float4(clampf(u4.x, 0.f, 2.f), clampf(v4.x, 0.f, 2.f),
                             clampf(u4.y, 0.f, 2.f), clampf(v4.y, 0.f, 2.f));
        dst[1] = make_float4(clampf(u4.z, 0.f, 2.f), clampf(v4.z, 0.f, 2.f),
                             clampf(u4.w, 0.f, 2.f), clampf(v4.w, 0.f, 2.f));
    }
    __syncthreads();

    int b = 0;

    // One fused step: region rows/cols [s, 95-s]; NC/C4LO compile-time.
#define GS_STEP(S, NC, C4LO)                                                     \
    {                                                                            \
        const float2* __restrict__ cb = sUV[b];                                  \
        float2* __restrict__ nb = sUV[b ^ 1];                                    \
        const int rlo   = (S);                                                   \
        const int npair = (P - 2 * (S)) >> 1;                                    \
        const int tasks = npair * (NC);                                          \
        for (int t = tid; t < tasks; t += NTHREADS) {                            \
            const int pr  = t / (NC);             /* compile-time magic mul */   \
            const int row = rlo + 2 * pr;                                        \
            const int c4  = (C4LO) + (t - pr * (NC)) * 4;                        \
            const float2* rA = cb + row * PITCH;                                 \
            const float2* rN = rA - PITCH;                                       \
            const float2* rB = rA + PITCH;                                       \
            const float2* rS = rB + PITCH;                                       \
            const int lc = (c4 > 0) ? c4 - 1 : 0;                                \
            const int rc = (c4 + 4 < P) ? c4 + 4 : P - 1;                        \
            const float4 n01 = ld4(rN + c4), n23 = ld4(rN + c4 + 2);             \
            const float4 a01 = ld4(rA + c4), a23 = ld4(rA + c4 + 2);             \
            const float4 b01 = ld4(rB + c4), b23 = ld4(rB + c4 + 2);             \
            const float4 s01 = ld4(rS + c4), s23 = ld4(rS + c4 + 2);             \
            const float2 eLa = rA[lc], eRa = rA[rc];                             \
            const float2 eLb = rB[lc], eRb = rB[rc];                             \
            const float ua[6]  = { eLa.x, a01.x, a01.z, a23.x, a23.z, eRa.x };   \
            const float va[6]  = { eLa.y, a01.y, a01.w, a23.y, a23.w, eRa.y };   \
            const float ub[6]  = { eLb.x, b01.x, b01.z, b23.x, b23.z, eRb.x };   \
            const float vb[6]  = { eLb.y, b01.y, b01.w, b23.y, b23.w, eRb.y };   \
            const float unn[4] = { n01.x, n01.z, n23.x, n23.z };                 \
            const float vnn[4] = { n01.y, n01.w, n23.y, n23.w };                 \
            const float uss[4] = { s01.x, s01.z, s23.x, s23.z };                 \
            const float vss[4] = { s01.y, s01.w, s23.y, s23.w };                 \
            float oua[4], ova[4], oub[4], ovb[4];                                \
            _Pragma("unroll")                                                    \
            for (int e = 0; e < 4; ++e) {                                        \
                {                                                                \
                    const float uc = ua[e + 1], vc = va[e + 1];                  \
                    float lu = (ua[e] + ua[e + 2] - 2.0f * uc) * invDX2          \
                             + (unn[e] + ub[e + 1] - 2.0f * uc) * invDY2;        \
                    float lv = (va[e] + va[e + 2] - 2.0f * vc) * invDX2          \
                             + (vnn[e] + vb[e + 1] - 2.0f * vc) * invDY2;        \
                    lu = clampf(lu, -10.0f, 10.0f);                              \
                    lv = clampf(lv, -10.0f, 10.0f);                              \
                    const float uvv = uc * vc * vc;                              \
                    const float du = clampf(fmaf(Du, lu, fmaf(f, 1.0f - uc, -uvv)), -1.0f, 1.0f); \
                    const float dv = clampf(fmaf(Dv, lv, uvv - fk * vc), -1.0f, 1.0f);            \
                    oua[e] = clampf(fmaf(du, dt, uc), 0.0f, 2.0f);               \
                    ova[e] = clampf(fmaf(dv, dt, vc), 0.0f, 2.0f);               \
                }                                                                \
                {                                                                \
                    const float uc = ub[e + 1], vc = vb[e + 1];                  \
                    float lu = (ub[e] + ub[e + 2] - 2.0f * uc) * invDX2          \
                             + (ua[e + 1] + uss[e] - 2.0f * uc) * invDY2;        \
                    float lv = (vb[e] + vb[e + 2] - 2.0f * vc) * invDX2          \
                             + (va[e + 1] + vss[e] - 2.0f * vc) * invDY2;        \
                    lu = clampf(lu, -10.0f, 10.0f);                              \
                    lv = clampf(lv, -10.0f, 10.0f);                              \
                    const float uvv = uc * vc * vc;                              \
                    const float du = clampf(fmaf(Du, lu, fmaf(f, 1.0f - uc, -uvv)), -1.0f, 1.0f); \
                    const float dv = clampf(fmaf(Dv, lv, uvv - fk * vc), -1.0f, 1.0f);            \
                    oub[e] = clampf(fmaf(du, dt, uc), 0.0f, 2.0f);               \
                    ovb[e] = clampf(fmaf(dv, dt, vc), 0.0f, 2.0f);               \
                }                                                                \
            }                                                                    \
            float4* dstA = reinterpret_cast<float4*>(nb + row * PITCH + c4);     \
            dstA[0] = make_float4(oua[0], ova[0], oua[1], ova[1]);               \
            dstA[1] = make_float4(oua[2], ova[2], oua[3], ova[3]);               \
            float4* dstB = reinterpret_cast<float4*>(nb + (row + 1) * PITCH + c4); \
            dstB[0] = make_float4(oub[0], ovb[0], oub[1], ovb[1]);               \
            dstB[1] = make_float4(oub[2], ovb[2], oub[3], ovb[3]);               \
        }                                                                        \
        b ^= 1;                                                                  \
        __syncthreads();                                                         \
    }

    // Steps grouped by constant nc (strips covering [s, 95-s]):
    for (int s = 1; s <= 3; ++s)   GS_STEP(s,  24,  0);   // s=1..3
    for (int s = 4; s <= 7; ++s)   GS_STEP(s,  22,  4);   // s=4..7
    for (int s = 8; s <= 11; ++s)  GS_STEP(s,  20,  8);   // s=8..11
    for (int s = 12; s <= 15; ++s) GS_STEP(s,  18, 12);   // s=12..15
    GS_STEP(16, 16, 16);                                  // s=16
#undef GS_STEP

    // ---- store the valid 64x64 interior, de-interleaving (b==0: 16 steps) ----
    const float2* __restrict__ fb = sUV[b];
    for (int i = tid; i < TILE * (TILE / 4); i += NTHREADS) {   // 1024 strips
        const int r  = i / (TILE / 4);
        const int c4 = (i - r * (TILE / 4)) * 4;
        const float4* src = reinterpret_cast<const float4*>(
            fb + (r + HALO) * PITCH + (c4 + HALO));
        const float4 a = src[0];
        const float4 q = src[1];
        const int go = (by * TILE + r) * W + bx * TILE + c4;
        *reinterpret_cast<float4*>(Uout + go) = make_float4(a.x, a.z, q.x, q.z);
        *reinterpret_cast<float4*>(Vout + go) = make_float4(a.y, a.w, q.y, q.w);
    }
}

} // namespace

extern "C" void kernel_launch(void* const* d_in, const int* in_sizes, int n_in,
                              void* d_out, int out_size, void* d_ws, size_t ws_size,
                              hipStream_t stream) {
    const float* U0     = (const float*)d_in[0];
    const float* V0     = (const float*)d_in[1];
    const float* pLogDu = (const float*)d_in[2];
    const float* pLogDv = (const float*)d_in[3];
    const float* pf     = (const float*)d_in[4];
    const float* pk     = (const float*)d_in[5];
    // d_in[6] = steps (int32) — fixed at 64 by the problem definition.

    float* wsU  = (float*)d_ws;   // 4 MB
    float* wsV  = wsU + HW;       // 4 MB
    float* outU = (float*)d_out;  // output layout: [U (HW) | V (HW)]
    float* outV = outU + HW;

    const double dx  = 1.0 / (W - 1);
    const double dy  = 1.0 / (H - 1);
    const double dx2 = dx * dx;
    const double dy2 = dy * dy;
    const float invdx2 = (float)(1.0 / dx2);
    const float invdy2 = (float)(1.0 / dy2);
    const float dtf    = (float)(0.1 * ((dx2 < dy2) ? dx2 : dy2) / (4.0 * 0.16));

    const int grid = (H / TILE) * (W / TILE);   // 256 blocks = 1 per CU

    // 4 launches of 16 fused steps, ping-pong ws <-> d_out; launch 3 (odd)
    // leaves the final state exactly in d_out.
    const float* cu = U0;
    const float* cv = V0;
    for (int l = 0; l < NLAUNCH; ++l) {
        float* nu;
        float* nv;
        if (l & 1) { nu = outU; nv = outV; }
        else       { nu = wsU;  nv = wsV;  }
        gs_tile<<<grid, NTHREADS, 0, stream>>>(cu, cv, nu, nv,
                                               pLogDu, pLogDv, pf, pk,
                                               invdx2, invdy2, dtf);
        cu = nu; cv = nv;
    }
}

// Round 7
// 126.176 us; speedup vs baseline: 3.0206x; 1.0604x over previous
//
#include <hip/hip_runtime.h>
#include <math.h>

namespace {

constexpr int H = 1024;
constexpr int W = 1024;
constexpr int HW = H * W;
constexpr int STEPS = 64;            // fixed by setup_inputs()
constexpr int TILE = 64;             // output tile edge
constexpr int HALO = 16;             // = steps fused per launch
constexpr int P = TILE + 2 * HALO;   // 96
constexpr int TSTEP = 16;            // time steps per kernel launch
constexpr int NLAUNCH = STEPS / TSTEP;   // 4
constexpr int NTX = W / TILE;        // 16 tiles per dim
constexpr int NTHREADS = 1024;       // 16 waves = 4/SIMD
constexpr int PITCHF = P + 4;        // 100 floats/row: 400B rows keep b128 align,
                                     // shift banks by 4 words per row

__device__ __forceinline__ float clampf(float v, float lo, float hi) {
    return fminf(fmaxf(v, lo), hi);
}
__device__ __forceinline__ float4 ld4f(const float* p) {
    return *reinterpret_cast<const float4*>(p);
}

// 16 fused Gray-Scott steps on a 64x64 tile, halo 16. U and V in SEPARATE
// double-buffered LDS arrays (de-interleaved): a 4-px strip = one b128 per
// field at 4-word lane stride -> 2-way bank access (free), vs 4-way conflicts
// of the interleaved float2 layout. Step s computes only rows/cols [s, 95-s];
// each task is a 2-row x 4-col block; the garbage ring outside the shrinking
// valid region is clamped-finite and never read by later steps.
__global__ __launch_bounds__(NTHREADS) void gs_tile(
    const float* __restrict__ Uin, const float* __restrict__ Vin,
    float* __restrict__ Uout, float* __restrict__ Vout,
    const float* __restrict__ pLogDu, const float* __restrict__ pLogDv,
    const float* __restrict__ pf, const float* __restrict__ pk,
    float invDX2, float invDY2, float dt)
{
    __shared__ __align__(16) float sU[2][P * PITCHF];   // 2 x 38.4 KB
    __shared__ __align__(16) float sV[2][P * PITCHF];   // total 153.6 KB

    const int tid = threadIdx.x;
    const int bx = blockIdx.x & (NTX - 1);
    const int by = blockIdx.x >> 4;
    const int gx0 = bx * TILE - HALO;
    const int gy0 = by * TILE - HALO;

    const float Du = clampf(expf(pLogDu[0]), 0.001f, 1.0f);
    const float Dv = clampf(expf(pLogDv[0]), 0.001f, 1.0f);
    const float f = pf[0], k = pk[0];
    const float fk = f + k;

    // ---- load 96x96 halo'd tile (periodic wrap) ----
    for (int t = tid; t < P * (P / 4); t += NTHREADS) {   // 2304 4-px strips
        const int r  = t / (P / 4);
        const int c4 = (t - r * (P / 4)) * 4;
        const int gy = (gy0 + r) & (H - 1);
        const int gx = (gx0 + c4) & (W - 1);              // 4-aligned, no mid-vec wrap
        const float4 u4 = *reinterpret_cast<const float4*>(Uin + gy * W + gx);
        const float4 v4 = *reinterpret_cast<const float4*>(Vin + gy * W + gx);
        *reinterpret_cast<float4*>(&sU[0][r * PITCHF + c4]) =
            make_float4(clampf(u4.x, 0.f, 2.f), clampf(u4.y, 0.f, 2.f),
                        clampf(u4.z, 0.f, 2.f), clampf(u4.w, 0.f, 2.f));
        *reinterpret_cast<float4*>(&sV[0][r * PITCHF + c4]) =
            make_float4(clampf(v4.x, 0.f, 2.f), clampf(v4.y, 0.f, 2.f),
                        clampf(v4.z, 0.f, 2.f), clampf(v4.w, 0.f, 2.f));
    }
    __syncthreads();

    int b = 0;

    // One fused step: region rows/cols [s, 95-s]; NC/C4LO compile-time.
#define GS_STEP(S, NC, C4LO)                                                     \
    {                                                                            \
        const float* __restrict__ cU = sU[b];                                    \
        const float* __restrict__ cV = sV[b];                                    \
        float* __restrict__ nU = sU[b ^ 1];                                      \
        float* __restrict__ nV = sV[b ^ 1];                                      \
        const int rlo   = (S);                                                   \
        const int npair = (P - 2 * (S)) >> 1;                                    \
        const int tasks = npair * (NC);                                          \
        for (int t = tid; t < tasks; t += NTHREADS) {                            \
            const int pr  = t / (NC);             /* compile-time magic mul */   \
            const int row = rlo + 2 * pr;                                        \
            const int c4  = (C4LO) + (t - pr * (NC)) * 4;                        \
            const int oA  = row * PITCHF + c4;                                   \
            const int lc  = (c4 > 0) ? c4 - 1 : 0;                               \
            const int rc  = (c4 + 4 < P) ? c4 + 4 : P - 1;                       \
            const float4 uN = ld4f(cU + oA - PITCHF);                            \
            const float4 uA = ld4f(cU + oA);                                     \
            const float4 uB = ld4f(cU + oA + PITCHF);                            \
            const float4 uS = ld4f(cU + oA + 2 * PITCHF);                        \
            const float4 vN = ld4f(cV + oA - PITCHF);                            \
            const float4 vA = ld4f(cV + oA);                                     \
            const float4 vB = ld4f(cV + oA + PITCHF);                            \
            const float4 vS = ld4f(cV + oA + 2 * PITCHF);                        \
            const float uLa = cU[row * PITCHF + lc], uRa = cU[row * PITCHF + rc];        \
            const float uLb = cU[(row + 1) * PITCHF + lc], uRb = cU[(row + 1) * PITCHF + rc]; \
            const float vLa = cV[row * PITCHF + lc], vRa = cV[row * PITCHF + rc];        \
            const float vLb = cV[(row + 1) * PITCHF + lc], vRb = cV[(row + 1) * PITCHF + rc]; \
            const float ua[6]  = { uLa, uA.x, uA.y, uA.z, uA.w, uRa };           \
            const float va[6]  = { vLa, vA.x, vA.y, vA.z, vA.w, vRa };           \
            const float ub[6]  = { uLb, uB.x, uB.y, uB.z, uB.w, uRb };           \
            const float vb[6]  = { vLb, vB.x, vB.y, vB.z, vB.w, vRb };           \
            const float unn[4] = { uN.x, uN.y, uN.z, uN.w };                     \
            const float vnn[4] = { vN.x, vN.y, vN.z, vN.w };                     \
            const float uss[4] = { uS.x, uS.y, uS.z, uS.w };                     \
            const float vss[4] = { vS.x, vS.y, vS.z, vS.w };                     \
            float oua[4], ova[4], oub[4], ovb[4];                                \
            _Pragma("unroll")                                                    \
            for (int e = 0; e < 4; ++e) {                                        \
                {                                                                \
                    const float uc = ua[e + 1], vc = va[e + 1];                  \
                    float lu = (ua[e] + ua[e + 2] - 2.0f * uc) * invDX2          \
                             + (unn[e] + ub[e + 1] - 2.0f * uc) * invDY2;        \
                    float lv = (va[e] + va[e + 2] - 2.0f * vc) * invDX2          \
                             + (vnn[e] + vb[e + 1] - 2.0f * vc) * invDY2;        \
                    lu = clampf(lu, -10.0f, 10.0f);                              \
                    lv = clampf(lv, -10.0f, 10.0f);                              \
                    const float uvv = uc * vc * vc;                              \
                    const float du = clampf(fmaf(Du, lu, fmaf(f, 1.0f - uc, -uvv)), -1.0f, 1.0f); \
                    const float dv = clampf(fmaf(Dv, lv, uvv - fk * vc), -1.0f, 1.0f);            \
                    oua[e] = clampf(fmaf(du, dt, uc), 0.0f, 2.0f);               \
                    ova[e] = clampf(fmaf(dv, dt, vc), 0.0f, 2.0f);               \
                }                                                                \
                {                                                                \
                    const float uc = ub[e + 1], vc = vb[e + 1];                  \
                    float lu = (ub[e] + ub[e + 2] - 2.0f * uc) * invDX2          \
                             + (ua[e + 1] + uss[e] - 2.0f * uc) * invDY2;        \
                    float lv = (vb[e] + vb[e + 2] - 2.0f * vc) * invDX2          \
                             + (va[e + 1] + vss[e] - 2.0f * vc) * invDY2;        \
                    lu = clampf(lu, -10.0f, 10.0f);                              \
                    lv = clampf(lv, -10.0f, 10.0f);                              \
                    const float uvv = uc * vc * vc;                              \
                    const float du = clampf(fmaf(Du, lu, fmaf(f, 1.0f - uc, -uvv)), -1.0f, 1.0f); \
                    const float dv = clampf(fmaf(Dv, lv, uvv - fk * vc), -1.0f, 1.0f);            \
                    oub[e] = clampf(fmaf(du, dt, uc), 0.0f, 2.0f);               \
                    ovb[e] = clampf(fmaf(dv, dt, vc), 0.0f, 2.0f);               \
                }                                                                \
            }                                                                    \
            *reinterpret_cast<float4*>(nU + oA)          = make_float4(oua[0], oua[1], oua[2], oua[3]); \
            *reinterpret_cast<float4*>(nU + oA + PITCHF) = make_float4(oub[0], oub[1], oub[2], oub[3]); \
            *reinterpret_cast<float4*>(nV + oA)          = make_float4(ova[0], ova[1], ova[2], ova[3]); \
            *reinterpret_cast<float4*>(nV + oA + PITCHF) = make_float4(ovb[0], ovb[1], ovb[2], ovb[3]); \
        }                                                                        \
        b ^= 1;                                                                  \
        __syncthreads();                                                         \
    }

    // Steps grouped by constant nc (strips covering [s, 95-s]):
    for (int s = 1; s <= 3; ++s)   GS_STEP(s,  24,  0);   // s=1..3
    for (int s = 4; s <= 7; ++s)   GS_STEP(s,  22,  4);   // s=4..7
    for (int s = 8; s <= 11; ++s)  GS_STEP(s,  20,  8);   // s=8..11
    for (int s = 12; s <= 15; ++s) GS_STEP(s,  18, 12);   // s=12..15
    GS_STEP(16, 16, 16);                                  // s=16
#undef GS_STEP

    // ---- store the valid 64x64 interior (b==0 after 16 steps) ----
    const float* __restrict__ fU = sU[b];
    const float* __restrict__ fV = sV[b];
    for (int i = tid; i < TILE * (TILE / 4); i += NTHREADS) {   // 1024 strips
        const int r  = i / (TILE / 4);
        const int c4 = (i - r * (TILE / 4)) * 4;
        const int li = (r + HALO) * PITCHF + (c4 + HALO);
        const int go = (by * TILE + r) * W + bx * TILE + c4;
        *reinterpret_cast<float4*>(Uout + go) = ld4f(fU + li);
        *reinterpret_cast<float4*>(Vout + go) = ld4f(fV + li);
    }
}

} // namespace

extern "C" void kernel_launch(void* const* d_in, const int* in_sizes, int n_in,
                              void* d_out, int out_size, void* d_ws, size_t ws_size,
                              hipStream_t stream) {
    const float* U0     = (const float*)d_in[0];
    const float* V0     = (const float*)d_in[1];
    const float* pLogDu = (const float*)d_in[2];
    const float* pLogDv = (const float*)d_in[3];
    const float* pf     = (const float*)d_in[4];
    const float* pk     = (const float*)d_in[5];
    // d_in[6] = steps (int32) — fixed at 64 by the problem definition.

    float* wsU  = (float*)d_ws;   // 4 MB
    float* wsV  = wsU + HW;       // 4 MB
    float* outU = (float*)d_out;  // output layout: [U (HW) | V (HW)]
    float* outV = outU + HW;

    const double dx  = 1.0 / (W - 1);
    const double dy  = 1.0 / (H - 1);
    const double dx2 = dx * dx;
    const double dy2 = dy * dy;
    const float invdx2 = (float)(1.0 / dx2);
    const float invdy2 = (float)(1.0 / dy2);
    const float dtf    = (float)(0.1 * ((dx2 < dy2) ? dx2 : dy2) / (4.0 * 0.16));

    const int grid = (H / TILE) * (W / TILE);   // 256 blocks = 1 per CU

    // 4 launches of 16 fused steps, ping-pong ws <-> d_out; launch 3 (odd)
    // leaves the final state exactly in d_out.
    const float* cu = U0;
    const float* cv = V0;
    for (int l = 0; l < NLAUNCH; ++l) {
        float* nu;
        float* nv;
        if (l & 1) { nu = outU; nv = outV; }
        else       { nu = wsU;  nv = wsV;  }
        gs_tile<<<grid, NTHREADS, 0, stream>>>(cu, cv, nu, nv,
                                               pLogDu, pLogDv, pf, pk,
                                               invdx2, invdy2, dtf);
        cu = nu; cv = nv;
    }
}

// Round 8
// 123.668 us; speedup vs baseline: 3.0818x; 1.0203x over previous
//
#include <hip/hip_runtime.h>
#include <math.h>

namespace {

constexpr int H = 1024;
constexpr int W = 1024;
constexpr int HW = H * W;
constexpr int STEPS = 64;            // fixed by setup_inputs()
constexpr int TILE = 64;             // output tile edge
constexpr int HALO = 16;             // = steps fused per launch
constexpr int P = TILE + 2 * HALO;   // 96
constexpr int TSTEP = 16;            // time steps per kernel launch
constexpr int NLAUNCH = STEPS / TSTEP;   // 4
constexpr int NTX = W / TILE;        // 16 tiles per dim
constexpr int NTHREADS = 1024;       // 16 waves = 4/SIMD
constexpr int PITCHF = P + 4;        // 100 floats/row: 400B rows keep b128 align

typedef float f2 __attribute__((ext_vector_type(2)));
typedef float f4 __attribute__((ext_vector_type(4)));

__device__ __forceinline__ float clampf(float v, float lo, float hi) {
    return fminf(fmaxf(v, lo), hi);           // -> v_med3_f32
}
__device__ __forceinline__ f2 clamp2(f2 v, float lo, float hi) {
    f2 r;
    r.x = fminf(fmaxf(v.x, lo), hi);          // -> 2x v_med3_f32 (no pk min/max)
    r.y = fminf(fmaxf(v.y, lo), hi);
    return r;
}
__device__ __forceinline__ f2 lo2(f4 q) { return __builtin_shufflevector(q, q, 0, 1); }
__device__ __forceinline__ f2 hi2(f4 q) { return __builtin_shufflevector(q, q, 2, 3); }
__device__ __forceinline__ f4 ld4f(const float* p) {
    return *reinterpret_cast<const f4*>(p);
}

// One Gray-Scott step for a 4-px row segment, both fields, packed 2-wide
// (v_pk_fma_f32/v_pk_add_f32/v_pk_mul_f32 from <2 x float> IR).
__device__ __forceinline__ void row_step(
    f4 uN, f4 uC, f4 uD, float uL, float uR,
    f4 vN, f4 vC, f4 vD, float vL, float vR,
    float ix2, float iy2, float Du, float Dv, float f, float fk, float dt,
    f4* outU, f4* outV)
{
    const f2 a0u = lo2(uC), a1u = hi2(uC);
    const f2 a0v = lo2(vC), a1v = hi2(vC);
    const f2 n0u = lo2(uN), n1u = hi2(uN);
    const f2 n0v = lo2(vN), n1v = hi2(vN);
    const f2 b0u = lo2(uD), b1u = hi2(uD);
    const f2 b0v = lo2(vD), b1v = hi2(vD);

    const f2 l0u = { uL, a0u.x };             // left-shifted pairs
    const f2 mmu = { a0u.y, a1u.x };          // shared middle pair
    const f2 r1u = { a1u.y, uR };
    const f2 l0v = { vL, a0v.x };
    const f2 mmv = { a0v.y, a1v.x };
    const f2 r1v = { a1v.y, vR };

    const f2 lu0 = clamp2((l0u + mmu - 2.0f * a0u) * ix2
                        + (n0u + b0u - 2.0f * a0u) * iy2, -10.0f, 10.0f);
    const f2 lu1 = clamp2((mmu + r1u - 2.0f * a1u) * ix2
                        + (n1u + b1u - 2.0f * a1u) * iy2, -10.0f, 10.0f);
    const f2 lv0 = clamp2((l0v + mmv - 2.0f * a0v) * ix2
                        + (n0v + b0v - 2.0f * a0v) * iy2, -10.0f, 10.0f);
    const f2 lv1 = clamp2((mmv + r1v - 2.0f * a1v) * ix2
                        + (n1v + b1v - 2.0f * a1v) * iy2, -10.0f, 10.0f);

    const f2 uvv0 = a0u * a0v * a0v;
    const f2 uvv1 = a1u * a1v * a1v;

    const f2 du0 = clamp2(Du * lu0 - uvv0 + f * (1.0f - a0u), -1.0f, 1.0f);
    const f2 du1 = clamp2(Du * lu1 - uvv1 + f * (1.0f - a1u), -1.0f, 1.0f);
    const f2 dv0 = clamp2(Dv * lv0 + uvv0 - fk * a0v, -1.0f, 1.0f);
    const f2 dv1 = clamp2(Dv * lv1 + uvv1 - fk * a1v, -1.0f, 1.0f);

    const f2 ou0 = clamp2(a0u + du0 * dt, 0.0f, 2.0f);
    const f2 ou1 = clamp2(a1u + du1 * dt, 0.0f, 2.0f);
    const f2 ov0 = clamp2(a0v + dv0 * dt, 0.0f, 2.0f);
    const f2 ov1 = clamp2(a1v + dv1 * dt, 0.0f, 2.0f);

    *outU = __builtin_shufflevector(ou0, ou1, 0, 1, 2, 3);
    *outV = __builtin_shufflevector(ov0, ov1, 0, 1, 2, 3);
}

// 16 fused Gray-Scott steps on a 64x64 tile, halo 16. U,V in separate
// double-buffered LDS arrays (conflict-free b128). Step s computes only
// rows/cols [s, 95-s]; each task = 2-row x 4-col block; the garbage ring
// outside the shrinking valid region is clamped-finite and never read.
__global__ __launch_bounds__(NTHREADS) void gs_tile(
    const float* __restrict__ Uin, const float* __restrict__ Vin,
    float* __restrict__ Uout, float* __restrict__ Vout,
    const float* __restrict__ pLogDu, const float* __restrict__ pLogDv,
    const float* __restrict__ pf, const float* __restrict__ pk,
    float invDX2, float invDY2, float dt)
{
    __shared__ __align__(16) float sU[2][P * PITCHF];   // 2 x 38.4 KB
    __shared__ __align__(16) float sV[2][P * PITCHF];   // total 153.6 KB

    const int tid = threadIdx.x;
    const int bx = blockIdx.x & (NTX - 1);
    const int by = blockIdx.x >> 4;
    const int gx0 = bx * TILE - HALO;
    const int gy0 = by * TILE - HALO;

    const float Du = clampf(expf(pLogDu[0]), 0.001f, 1.0f);
    const float Dv = clampf(expf(pLogDv[0]), 0.001f, 1.0f);
    const float f = pf[0], k = pk[0];
    const float fk = f + k;

    // ---- load 96x96 halo'd tile (periodic wrap) ----
    for (int t = tid; t < P * (P / 4); t += NTHREADS) {   // 2304 4-px strips
        const int r  = t / (P / 4);
        const int c4 = (t - r * (P / 4)) * 4;
        const int gy = (gy0 + r) & (H - 1);
        const int gx = (gx0 + c4) & (W - 1);              // 4-aligned, no mid-vec wrap
        const float4 u4 = *reinterpret_cast<const float4*>(Uin + gy * W + gx);
        const float4 v4 = *reinterpret_cast<const float4*>(Vin + gy * W + gx);
        *reinterpret_cast<float4*>(&sU[0][r * PITCHF + c4]) =
            make_float4(clampf(u4.x, 0.f, 2.f), clampf(u4.y, 0.f, 2.f),
                        clampf(u4.z, 0.f, 2.f), clampf(u4.w, 0.f, 2.f));
        *reinterpret_cast<float4*>(&sV[0][r * PITCHF + c4]) =
            make_float4(clampf(v4.x, 0.f, 2.f), clampf(v4.y, 0.f, 2.f),
                        clampf(v4.z, 0.f, 2.f), clampf(v4.w, 0.f, 2.f));
    }
    __syncthreads();

    int b = 0;

    // One fused step: region rows/cols [s, 95-s]; NC/C4LO compile-time.
#define GS_STEP(S, NC, C4LO)                                                     \
    {                                                                            \
        const float* __restrict__ cU = sU[b];                                    \
        const float* __restrict__ cV = sV[b];                                    \
        float* __restrict__ nU = sU[b ^ 1];                                      \
        float* __restrict__ nV = sV[b ^ 1];                                      \
        const int rlo   = (S);                                                   \
        const int npair = (P - 2 * (S)) >> 1;                                    \
        const int tasks = npair * (NC);                                          \
        for (int t = tid; t < tasks; t += NTHREADS) {                            \
            const int pr  = t / (NC);             /* compile-time magic mul */   \
            const int row = rlo + 2 * pr;                                        \
            const int c4  = (C4LO) + (t - pr * (NC)) * 4;                        \
            const int oA  = row * PITCHF + c4;                                   \
            const int lc  = (c4 > 0) ? c4 - 1 : 0;                               \
            const int rc  = (c4 + 4 < P) ? c4 + 4 : P - 1;                       \
            const f4 uN = ld4f(cU + oA - PITCHF);                                \
            const f4 uA = ld4f(cU + oA);                                         \
            const f4 uB = ld4f(cU + oA + PITCHF);                                \
            const f4 uS = ld4f(cU + oA + 2 * PITCHF);                            \
            const f4 vN = ld4f(cV + oA - PITCHF);                                \
            const f4 vA = ld4f(cV + oA);                                         \
            const f4 vB = ld4f(cV + oA + PITCHF);                                \
            const f4 vS = ld4f(cV + oA + 2 * PITCHF);                            \
            const float uLa = cU[row * PITCHF + lc], uRa = cU[row * PITCHF + rc];        \
            const float uLb = cU[(row + 1) * PITCHF + lc], uRb = cU[(row + 1) * PITCHF + rc]; \
            const float vLa = cV[row * PITCHF + lc], vRa = cV[row * PITCHF + rc];        \
            const float vLb = cV[(row + 1) * PITCHF + lc], vRb = cV[(row + 1) * PITCHF + rc]; \
            f4 ouA, ovA, ouB, ovB;                                               \
            row_step(uN, uA, uB, uLa, uRa, vN, vA, vB, vLa, vRa,                 \
                     invDX2, invDY2, Du, Dv, f, fk, dt, &ouA, &ovA);             \
            row_step(uA, uB, uS, uLb, uRb, vA, vB, vS, vLb, vRb,                 \
                     invDX2, invDY2, Du, Dv, f, fk, dt, &ouB, &ovB);             \
            *reinterpret_cast<f4*>(nU + oA)          = ouA;                      \
            *reinterpret_cast<f4*>(nU + oA + PITCHF) = ouB;                      \
            *reinterpret_cast<f4*>(nV + oA)          = ovA;                      \
            *reinterpret_cast<f4*>(nV + oA + PITCHF) = ovB;                      \
        }                                                                        \
        b ^= 1;                                                                  \
        __syncthreads();                                                         \
    }

    // Steps grouped by constant nc (strips covering [s, 95-s]):
    for (int s = 1; s <= 3; ++s)   GS_STEP(s,  24,  0);   // s=1..3
    for (int s = 4; s <= 7; ++s)   GS_STEP(s,  22,  4);   // s=4..7
    for (int s = 8; s <= 11; ++s)  GS_STEP(s,  20,  8);   // s=8..11
    for (int s = 12; s <= 15; ++s) GS_STEP(s,  18, 12);   // s=12..15
    GS_STEP(16, 16, 16);                                  // s=16
#undef GS_STEP

    // ---- store the valid 64x64 interior (b==0 after 16 steps) ----
    const float* __restrict__ fU = sU[b];
    const float* __restrict__ fV = sV[b];
    for (int i = tid; i < TILE * (TILE / 4); i += NTHREADS) {   // 1024 strips
        const int r  = i / (TILE / 4);
        const int c4 = (i - r * (TILE / 4)) * 4;
        const int li = (r + HALO) * PITCHF + (c4 + HALO);
        const int go = (by * TILE + r) * W + bx * TILE + c4;
        *reinterpret_cast<f4*>(Uout + go) = ld4f(fU + li);
        *reinterpret_cast<f4*>(Vout + go) = ld4f(fV + li);
    }
}

} // namespace

extern "C" void kernel_launch(void* const* d_in, const int* in_sizes, int n_in,
                              void* d_out, int out_size, void* d_ws, size_t ws_size,
                              hipStream_t stream) {
    const float* U0     = (const float*)d_in[0];
    const float* V0     = (const float*)d_in[1];
    const float* pLogDu = (const float*)d_in[2];
    const float* pLogDv = (const float*)d_in[3];
    const float* pf     = (const float*)d_in[4];
    const float* pk     = (const float*)d_in[5];
    // d_in[6] = steps (int32) — fixed at 64 by the problem definition.

    float* wsU  = (float*)d_ws;   // 4 MB
    float* wsV  = wsU + HW;       // 4 MB
    float* outU = (float*)d_out;  // output layout: [U (HW) | V (HW)]
    float* outV = outU + HW;

    const double dx  = 1.0 / (W - 1);
    const double dy  = 1.0 / (H - 1);
    const double dx2 = dx * dx;
    const double dy2 = dy * dy;
    const float invdx2 = (float)(1.0 / dx2);
    const float invdy2 = (float)(1.0 / dy2);
    const float dtf    = (float)(0.1 * ((dx2 < dy2) ? dx2 : dy2) / (4.0 * 0.16));

    const int grid = (H / TILE) * (W / TILE);   // 256 blocks = 1 per CU

    // 4 launches of 16 fused steps, ping-pong ws <-> d_out; launch 3 (odd)
    // leaves the final state exactly in d_out.
    const float* cu = U0;
    const float* cv = V0;
    for (int l = 0; l < NLAUNCH; ++l) {
        float* nu;
        float* nv;
        if (l & 1) { nu = outU; nv = outV; }
        else       { nu = wsU;  nv = wsV;  }
        gs_tile<<<grid, NTHREADS, 0, stream>>>(cu, cv, nu, nv,
                                               pLogDu, pLogDv, pf, pk,
                                               invdx2, invdy2, dtf);
        cu = nu; cv = nv;
    }
}